// Round 1
// baseline (1359.235 us; speedup 1.0000x reference)
//
#include <hip/hip_runtime.h>
#include <math.h>

#define T_TOK 2048
#define NE 64
#define KTOP 8
#define CAPC 512
#define DIN 768
#define HD 2048
#define BTD 256
#define OD 768

typedef short bf16x8 __attribute__((ext_vector_type(8)));
typedef float f32x4 __attribute__((ext_vector_type(4)));

__device__ __forceinline__ unsigned short f2bf(float f) {
  unsigned u = __float_as_uint(f);
  u += 0x7FFF + ((u >> 16) & 1);   // round-to-nearest-even
  return (unsigned short)(u >> 16);
}
__device__ __forceinline__ float gelu_exact(float v) {
  return 0.5f * v * (1.0f + erff(v * 0.7071067811865476f));
}

// ---------------- router: fp32 logits, noisy top-8, softmax, gate/slot matrices ----
__global__ __launch_bounds__(256) void router_kernel(
    const float* __restrict__ x, const float* __restrict__ noise,
    const float* __restrict__ Wr, const float* __restrict__ br,
    const float* __restrict__ Wn, const float* __restrict__ bn,
    float* __restrict__ gate, int* __restrict__ slotm)
{
  __shared__ float xs[8][DIN];
  __shared__ float wrs[64][NE];
  __shared__ float wns[64][NE];
  const int tid = threadIdx.x;
  const int t0 = blockIdx.x * 8;
  for (int i = tid; i < 8 * (DIN / 4); i += 256) {
    int tt = i / (DIN / 4), c = i % (DIN / 4);
    ((float4*)xs[tt])[c] = ((const float4*)(x + (size_t)(t0 + tt) * DIN))[c];
  }
  const int lane = tid & 63;
  const int wv = tid >> 6;
  const int e = lane;
  const int ta = 2 * wv, tb = ta + 1;
  float ar0 = br[e], ar1 = ar0, an0 = bn[e], an1 = an0;
  for (int d0 = 0; d0 < DIN; d0 += 64) {
    __syncthreads();
    for (int i = tid; i < 64 * NE / 4; i += 256) {
      int dd = i >> 4, c4 = (i & 15) * 4;
      *(float4*)&wrs[dd][c4] = *(const float4*)&Wr[(size_t)(d0 + dd) * NE + c4];
      *(float4*)&wns[dd][c4] = *(const float4*)&Wn[(size_t)(d0 + dd) * NE + c4];
    }
    __syncthreads();
    #pragma unroll 8
    for (int dd = 0; dd < 64; dd++) {
      float wr = wrs[dd][e], wn = wns[dd][e];
      float xa = xs[ta][d0 + dd], xb = xs[tb][d0 + dd];
      ar0 = fmaf(xa, wr, ar0); ar1 = fmaf(xb, wr, ar1);
      an0 = fmaf(xa, wn, an0); an1 = fmaf(xb, wn, an1);
    }
  }
  #pragma unroll
  for (int s = 0; s < 2; s++) {
    int t = t0 + ta + s;
    float lr = s ? ar1 : ar0;
    float lnv = s ? an1 : an0;
    float sp = fmaxf(lnv, 0.f) + log1pf(expf(-fabsf(lnv)));   // softplus, overflow-safe
    float v = lr + noise[(size_t)t * NE + e] * sp;
    float cur = v;
    float topv[KTOP]; int topi[KTOP];
    #pragma unroll
    for (int j = 0; j < KTOP; j++) {
      float bv = cur; int bi = e;
      #pragma unroll
      for (int off = 32; off > 0; off >>= 1) {
        float ov = __shfl_xor(bv, off);
        int   oi = __shfl_xor(bi, off);
        if (ov > bv || (ov == bv && oi < bi)) { bv = ov; bi = oi; }
      }
      topv[j] = bv; topi[j] = bi;
      if (e == bi) cur = -INFINITY;
    }
    float mx = topv[0], se = 0.f, pv[KTOP];
    #pragma unroll
    for (int j = 0; j < KTOP; j++) { pv[j] = expf(topv[j] - mx); se += pv[j]; }
    float inv = 1.f / se;
    float g = 0.f; int sl = -1;
    #pragma unroll
    for (int j = 0; j < KTOP; j++) if (topi[j] == e) { g = pv[j] * inv; sl = j; }
    gate[(size_t)t * NE + e] = (sl >= 0) ? g : 0.f;
    slotm[(size_t)t * NE + e] = sl;
  }
}

// ---------------- dispatch: stable per-expert compaction (== stable argsort) -------
__global__ __launch_bounds__(256) void dispatch_kernel(
    const float* __restrict__ gate, const int* __restrict__ slotm,
    int* __restrict__ tok_idx, float* __restrict__ tok_g,
    int* __restrict__ tok_slot, int* __restrict__ counts)
{
  const int e = blockIdx.x;
  const int tid = threadIdx.x;
  __shared__ int wave_off[4];
  int base = 0;
  for (int t0 = 0; t0 < T_TOK; t0 += 256) {
    int t = t0 + tid;
    float g = gate[(size_t)t * NE + e];
    bool p = g > 0.f;
    unsigned long long m = __ballot(p);
    int wv = tid >> 6, lane = tid & 63;
    int pre = __popcll(m & ((1ull << lane) - 1ull));
    if (lane == 0) wave_off[wv] = __popcll(m);
    __syncthreads();
    int off = 0;
    for (int w = 0; w < wv; w++) off += wave_off[w];
    int tot = wave_off[0] + wave_off[1] + wave_off[2] + wave_off[3];
    if (p) {
      int pos = base + off + pre;
      if (pos < CAPC) {
        tok_idx[(size_t)e * CAPC + pos] = t;
        tok_g[(size_t)e * CAPC + pos] = g;
        tok_slot[(size_t)e * CAPC + pos] = slotm[(size_t)t * NE + e];
      }
    }
    base += tot;
    __syncthreads();
  }
  if (tid == 0) counts[e] = min(base, CAPC);
}

// ---------------- expert GEMM: 128x128x32 tile, bf16 MFMA, fused epilogues ----------
// EPI: 0 = bias+gelu -> bf16   1 = bias -> bf16   2 = (bias)*g scatter -> f32 ydense
template<int KD, int ND, bool ABF16, int EPI>
__global__ __launch_bounds__(256) void moe_gemm(
    const void* __restrict__ Ap, const float* __restrict__ Bw,
    const float* __restrict__ bias, void* __restrict__ Outp,
    const int* __restrict__ tok_idx, const float* __restrict__ tok_g,
    const int* __restrict__ tok_slot, const int* __restrict__ counts)
{
  const int e = blockIdx.z;
  const int cnt = counts[e];
  const int m0 = blockIdx.y * 128;
  if (m0 >= cnt) return;
  const int n0 = blockIdx.x * 128;
  const int tid = threadIdx.x;

  __shared__ unsigned short Al[2][128][32];
  __shared__ unsigned short Bl[2][128][32];
  __shared__ int   s_tok[128];
  __shared__ float s_g[128];
  __shared__ int   s_slot[128];

  if (EPI == 2 && tid < 128) {
    int gr = m0 + tid;
    if (gr < cnt) {
      s_tok[tid]  = tok_idx[(size_t)e * CAPC + gr];
      s_g[tid]    = tok_g[(size_t)e * CAPC + gr];
      s_slot[tid] = tok_slot[(size_t)e * CAPC + gr];
    }
  }

  const bool isB = tid < 128;
  const int b_k0 = ((tid & 127) >> 5) << 3;   // 0,8,16,24
  const int b_nq = tid & 31;                  // col quad
  const int b_s  = (b_nq & 3) << 3;           // XOR swizzle for col 4*b_nq+i
  const int a_r  = tid & 127;                 // A row
  const int a_s  = ((a_r >> 2) & 3) << 3;
  const int a_gr = m0 + a_r;
  const bool a_valid = a_gr < cnt;
  int a_tok = 0;
  if (!ABF16 && !isB) a_tok = a_valid ? tok_idx[(size_t)e * CAPC + a_gr] : 0;

  const float* ax = (const float*)Ap;
  const unsigned short* ah = (const unsigned short*)Ap;
  const size_t b_base = (size_t)e * KD * ND + n0 + 4 * b_nq;
  const size_t a_base_h = ((size_t)e * CAPC + a_gr) * KD;
  const size_t a_base_x = (size_t)a_tok * DIN;

  float4 bv[8];
  uint4  av[4];

  auto load_tile = [&](int kt) {
    if (isB) {
      const float* bp = Bw + b_base + (size_t)(kt * 32 + b_k0) * ND;
      #pragma unroll
      for (int rr = 0; rr < 8; rr++) bv[rr] = *(const float4*)(bp + (size_t)rr * ND);
    } else if (ABF16) {
      if (a_valid) {
        const unsigned short* p = ah + a_base_h + kt * 32;
        #pragma unroll
        for (int j = 0; j < 4; j++) av[j] = *(const uint4*)(p + 8 * j);
      } else {
        #pragma unroll
        for (int j = 0; j < 4; j++) av[j] = make_uint4(0, 0, 0, 0);
      }
    } else {
      const float* p = ax + a_base_x + kt * 32;
      #pragma unroll
      for (int j = 0; j < 8; j++)
        bv[j] = a_valid ? *(const float4*)(p + 4 * j) : make_float4(0.f, 0.f, 0.f, 0.f);
    }
  };
  auto store_tile = [&](int buf) {
    if (isB) {
      #pragma unroll
      for (int i = 0; i < 4; i++) {      // transpose 8k x 4n -> 4 cols of 8 k
        union { bf16x8 v; unsigned short u[8]; } pk;
        #pragma unroll
        for (int rr = 0; rr < 8; rr++) pk.u[rr] = f2bf((&bv[rr].x)[i]);
        *(bf16x8*)&Bl[buf][4 * b_nq + i][b_k0 ^ b_s] = pk.v;
      }
    } else if (ABF16) {
      #pragma unroll
      for (int j = 0; j < 4; j++) *(uint4*)&Al[buf][a_r][(8 * j) ^ a_s] = av[j];
    } else {
      #pragma unroll
      for (int j = 0; j < 4; j++) {
        union { bf16x8 v; unsigned short u[8]; } pk;
        #pragma unroll
        for (int q = 0; q < 4; q++) pk.u[q]     = f2bf((&bv[2 * j].x)[q]);
        #pragma unroll
        for (int q = 0; q < 4; q++) pk.u[4 + q] = f2bf((&bv[2 * j + 1].x)[q]);
        *(bf16x8*)&Al[buf][a_r][(8 * j) ^ a_s] = pk.v;
      }
    }
  };

  load_tile(0);
  store_tile(0);
  __syncthreads();

  f32x4 acc[4][4];
  #pragma unroll
  for (int i = 0; i < 4; i++)
    #pragma unroll
    for (int j = 0; j < 4; j++) acc[i][j] = (f32x4){0.f, 0.f, 0.f, 0.f};

  const int lane = tid & 63, wv = tid >> 6;
  const int wm = (wv >> 1) * 64, wn = (wv & 1) * 64;
  const int li = lane & 15, lg = lane >> 4;
  const int kx = (lg * 8) ^ ((li >> 2) << 3);

  constexpr int NK = KD / 32;
  for (int kt = 0; kt < NK; kt++) {
    const int cur = kt & 1;
    if (kt + 1 < NK) load_tile(kt + 1);
    bf16x8 afr[4], bfr[4];
    #pragma unroll
    for (int mi = 0; mi < 4; mi++)
      afr[mi] = *(const bf16x8*)&Al[cur][wm + mi * 16 + li][kx];
    #pragma unroll
    for (int ni = 0; ni < 4; ni++)
      bfr[ni] = *(const bf16x8*)&Bl[cur][wn + ni * 16 + li][kx];
    #pragma unroll
    for (int mi = 0; mi < 4; mi++)
      #pragma unroll
      for (int ni = 0; ni < 4; ni++)
        acc[mi][ni] = __builtin_amdgcn_mfma_f32_16x16x32_bf16(afr[mi], bfr[ni], acc[mi][ni], 0, 0, 0);
    if (kt + 1 < NK) store_tile(cur ^ 1);
    __syncthreads();
  }

  const float* bp = bias + (size_t)e * ND;
  #pragma unroll
  for (int mi = 0; mi < 4; mi++) {
    #pragma unroll
    for (int ni = 0; ni < 4; ni++) {
      const int ncol = n0 + wn + ni * 16 + li;
      const float bb = bp[ncol];
      #pragma unroll
      for (int q = 0; q < 4; q++) {
        const int r = wm + mi * 16 + lg * 4 + q;
        const int gr = m0 + r;
        if (gr < cnt) {
          float v = acc[mi][ni][q] + bb;
          if (EPI == 0) {
            v = gelu_exact(v);
            ((unsigned short*)Outp)[((size_t)e * CAPC + gr) * ND + ncol] = f2bf(v);
          } else if (EPI == 1) {
            ((unsigned short*)Outp)[((size_t)e * CAPC + gr) * ND + ncol] = f2bf(v);
          } else {
            ((float*)Outp)[((size_t)s_tok[r] * KTOP + s_slot[r]) * OD + ncol] = v * s_g[r];
          }
        }
      }
    }
  }
}

// ---------------- combine 8 slots + LayerNorm -------------------------------------
__global__ __launch_bounds__(256) void combine_ln(
    const float* __restrict__ yd, const float* __restrict__ lw,
    const float* __restrict__ lb, float* __restrict__ out)
{
  const int t = blockIdx.x, tid = threadIdx.x;
  float v[3];
  #pragma unroll
  for (int i = 0; i < 3; i++) {
    const int c = tid + 256 * i;
    float s = 0.f;
    #pragma unroll
    for (int j = 0; j < KTOP; j++) s += yd[((size_t)t * KTOP + j) * OD + c];
    v[i] = s;
  }
  float s1 = v[0] + v[1] + v[2];
  float s2 = v[0] * v[0] + v[1] * v[1] + v[2] * v[2];
  #pragma unroll
  for (int off = 32; off > 0; off >>= 1) {
    s1 += __shfl_xor(s1, off);
    s2 += __shfl_xor(s2, off);
  }
  __shared__ float as1[4], as2[4];
  const int lane = tid & 63, wv = tid >> 6;
  if (lane == 0) { as1[wv] = s1; as2[wv] = s2; }
  __syncthreads();
  s1 = as1[0] + as1[1] + as1[2] + as1[3];
  s2 = as2[0] + as2[1] + as2[2] + as2[3];
  const float mu = s1 * (1.f / OD);
  const float var = s2 * (1.f / OD) - mu * mu;
  const float rstd = rsqrtf(var + 1e-5f);
  #pragma unroll
  for (int i = 0; i < 3; i++) {
    const int c = tid + 256 * i;
    out[(size_t)t * OD + c] = (v[i] - mu) * rstd * lw[c] + lb[c];
  }
}

extern "C" void kernel_launch(void* const* d_in, const int* in_sizes, int n_in,
                              void* d_out, int out_size, void* d_ws, size_t ws_size,
                              hipStream_t stream) {
  const float* x     = (const float*)d_in[0];
  const float* noise = (const float*)d_in[1];
  const float* Wr    = (const float*)d_in[2];
  const float* br    = (const float*)d_in[3];
  const float* Wn    = (const float*)d_in[4];
  const float* bn    = (const float*)d_in[5];
  const float* W1    = (const float*)d_in[6];
  const float* b1    = (const float*)d_in[7];
  const float* W2    = (const float*)d_in[8];
  const float* b2    = (const float*)d_in[9];
  const float* W3    = (const float*)d_in[10];
  const float* b3    = (const float*)d_in[11];
  const float* Wo    = (const float*)d_in[12];
  const float* bo    = (const float*)d_in[13];
  const float* lw    = (const float*)d_in[14];
  const float* lb    = (const float*)d_in[15];
  float* out = (float*)d_out;

  char* ws = (char*)d_ws;
  constexpr size_t OFF_GATE = 0;
  constexpr size_t OFF_SLOT = OFF_GATE + (size_t)T_TOK * NE * 4;
  constexpr size_t OFF_TIDX = OFF_SLOT + (size_t)T_TOK * NE * 4;
  constexpr size_t OFF_TG   = OFF_TIDX + (size_t)NE * CAPC * 4;
  constexpr size_t OFF_TSL  = OFF_TG + (size_t)NE * CAPC * 4;
  constexpr size_t OFF_CNT  = OFF_TSL + (size_t)NE * CAPC * 4;
  constexpr size_t OFF_YD   = ((OFF_CNT + NE * 4) + 255) & ~(size_t)255;
  constexpr size_t SZ_YD    = (size_t)T_TOK * KTOP * OD * 4;
  constexpr size_t OFF_H1   = OFF_YD + SZ_YD;
  constexpr size_t OFF_H2   = OFF_H1 + (size_t)NE * CAPC * HD * 2;
  constexpr size_t OFF_H3   = OFF_H2 + (size_t)NE * CAPC * HD * 2;

  float* gate = (float*)(ws + OFF_GATE);
  int*   slot = (int*)(ws + OFF_SLOT);
  int*   tidx = (int*)(ws + OFF_TIDX);
  float* tg   = (float*)(ws + OFF_TG);
  int*   tsl  = (int*)(ws + OFF_TSL);
  int*   cnts = (int*)(ws + OFF_CNT);
  float* yd   = (float*)(ws + OFF_YD);
  unsigned short* h1 = (unsigned short*)(ws + OFF_H1);
  unsigned short* h2 = (unsigned short*)(ws + OFF_H2);
  unsigned short* h3 = (unsigned short*)(ws + OFF_H3);

  hipMemsetAsync(yd, 0, SZ_YD, stream);
  router_kernel<<<T_TOK / 8, 256, 0, stream>>>(x, noise, Wr, br, Wn, bn, gate, slot);
  dispatch_kernel<<<NE, 256, 0, stream>>>(gate, slot, tidx, tg, tsl, cnts);
  moe_gemm<DIN, HD, false, 0><<<dim3(HD / 128, CAPC / 128, NE), 256, 0, stream>>>(
      x, W1, b1, h1, tidx, tg, tsl, cnts);
  moe_gemm<HD, HD, true, 0><<<dim3(HD / 128, CAPC / 128, NE), 256, 0, stream>>>(
      h1, W2, b2, h2, tidx, tg, tsl, cnts);
  moe_gemm<HD, BTD, true, 1><<<dim3(BTD / 128, CAPC / 128, NE), 256, 0, stream>>>(
      h2, W3, b3, h3, tidx, tg, tsl, cnts);
  moe_gemm<BTD, OD, true, 2><<<dim3(OD / 128, CAPC / 128, NE), 256, 0, stream>>>(
      h3, Wo, bo, yd, tidx, tg, tsl, cnts);
  combine_ln<<<T_TOK, 256, 0, stream>>>(yd, lw, lb, out);
}

// Round 2
// 1108.106 us; speedup vs baseline: 1.2266x; 1.2266x over previous
//
#include <hip/hip_runtime.h>
#include <math.h>

#define T_TOK 2048
#define NE 64
#define KTOP 8
#define CAPC 512
#define DIN 768
#define HD 2048
#define BTD 256
#define OD 768

typedef short bf16x8 __attribute__((ext_vector_type(8)));
typedef float f32x4 __attribute__((ext_vector_type(4)));

__device__ __forceinline__ unsigned short f2bf(float f) {
  unsigned u = __float_as_uint(f);
  u += 0x7FFF + ((u >> 16) & 1);   // round-to-nearest-even
  return (unsigned short)(u >> 16);
}
__device__ __forceinline__ float gelu_exact(float v) {
  return 0.5f * v * (1.0f + erff(v * 0.7071067811865476f));
}
__device__ __forceinline__ void glds16(unsigned short* lds, const unsigned short* g) {
  __builtin_amdgcn_global_load_lds(
      (const __attribute__((address_space(1))) void*)g,
      (__attribute__((address_space(3))) void*)lds, 16, 0, 0);
}
#define BAR() do { asm volatile("s_waitcnt lgkmcnt(0)" ::: "memory"); \
                   __builtin_amdgcn_s_barrier();                      \
                   asm volatile("" ::: "memory"); } while (0)

// ---------------- x fp32 -> bf16 ---------------------------------------------------
__global__ __launch_bounds__(256) void cvt_x(const float* __restrict__ x,
                                             unsigned short* __restrict__ xb) {
  int i = blockIdx.x * 256 + threadIdx.x;
  float4 v = ((const float4*)x)[i];
  ushort4 o;
  o.x = f2bf(v.x); o.y = f2bf(v.y); o.z = f2bf(v.z); o.w = f2bf(v.w);
  ((ushort4*)xb)[i] = o;
}

// ---------------- router: fp32 logits, noisy top-8, softmax, gate/slot matrices ----
__global__ __launch_bounds__(256) void router_kernel(
    const float* __restrict__ x, const float* __restrict__ noise,
    const float* __restrict__ Wr, const float* __restrict__ br,
    const float* __restrict__ Wn, const float* __restrict__ bn,
    float* __restrict__ gate, int* __restrict__ slotm)
{
  __shared__ float xs[8][DIN];
  __shared__ float wrs[64][NE];
  __shared__ float wns[64][NE];
  const int tid = threadIdx.x;
  const int t0 = blockIdx.x * 8;
  for (int i = tid; i < 8 * (DIN / 4); i += 256) {
    int tt = i / (DIN / 4), c = i % (DIN / 4);
    ((float4*)xs[tt])[c] = ((const float4*)(x + (size_t)(t0 + tt) * DIN))[c];
  }
  const int lane = tid & 63;
  const int wv = tid >> 6;
  const int e = lane;
  const int ta = 2 * wv, tb = ta + 1;
  float ar0 = br[e], ar1 = ar0, an0 = bn[e], an1 = an0;
  for (int d0 = 0; d0 < DIN; d0 += 64) {
    __syncthreads();
    for (int i = tid; i < 64 * NE / 4; i += 256) {
      int dd = i >> 4, c4 = (i & 15) * 4;
      *(float4*)&wrs[dd][c4] = *(const float4*)&Wr[(size_t)(d0 + dd) * NE + c4];
      *(float4*)&wns[dd][c4] = *(const float4*)&Wn[(size_t)(d0 + dd) * NE + c4];
    }
    __syncthreads();
    #pragma unroll 8
    for (int dd = 0; dd < 64; dd++) {
      float wr = wrs[dd][e], wn = wns[dd][e];
      float xa = xs[ta][d0 + dd], xb = xs[tb][d0 + dd];
      ar0 = fmaf(xa, wr, ar0); ar1 = fmaf(xb, wr, ar1);
      an0 = fmaf(xa, wn, an0); an1 = fmaf(xb, wn, an1);
    }
  }
  #pragma unroll
  for (int s = 0; s < 2; s++) {
    int t = t0 + ta + s;
    float lr = s ? ar1 : ar0;
    float lnv = s ? an1 : an0;
    float sp = fmaxf(lnv, 0.f) + log1pf(expf(-fabsf(lnv)));   // softplus, overflow-safe
    float v = lr + noise[(size_t)t * NE + e] * sp;
    float cur = v;
    float topv[KTOP]; int topi[KTOP];
    #pragma unroll
    for (int j = 0; j < KTOP; j++) {
      float bv = cur; int bi = e;
      #pragma unroll
      for (int off = 32; off > 0; off >>= 1) {
        float ov = __shfl_xor(bv, off);
        int   oi = __shfl_xor(bi, off);
        if (ov > bv || (ov == bv && oi < bi)) { bv = ov; bi = oi; }
      }
      topv[j] = bv; topi[j] = bi;
      if (e == bi) cur = -INFINITY;
    }
    float mx = topv[0], se = 0.f, pv[KTOP];
    #pragma unroll
    for (int j = 0; j < KTOP; j++) { pv[j] = expf(topv[j] - mx); se += pv[j]; }
    float inv = 1.f / se;
    float g = 0.f; int sl = -1;
    #pragma unroll
    for (int j = 0; j < KTOP; j++) if (topi[j] == e) { g = pv[j] * inv; sl = j; }
    gate[(size_t)t * NE + e] = (sl >= 0) ? g : 0.f;
    slotm[(size_t)t * NE + e] = sl;
  }
}

// ---------------- dispatch: stable per-expert compaction (== stable argsort) -------
__global__ __launch_bounds__(256) void dispatch_kernel(
    const float* __restrict__ gate, const int* __restrict__ slotm,
    int* __restrict__ tok_idx, float* __restrict__ tok_g,
    int* __restrict__ tok_slot, int* __restrict__ counts)
{
  const int e = blockIdx.x;
  const int tid = threadIdx.x;
  __shared__ int wave_off[4];
  int base = 0;
  for (int t0 = 0; t0 < T_TOK; t0 += 256) {
    int t = t0 + tid;
    float g = gate[(size_t)t * NE + e];
    bool p = g > 0.f;
    unsigned long long m = __ballot(p);
    int wv = tid >> 6, lane = tid & 63;
    int pre = __popcll(m & ((1ull << lane) - 1ull));
    if (lane == 0) wave_off[wv] = __popcll(m);
    __syncthreads();
    int off = 0;
    for (int w = 0; w < wv; w++) off += wave_off[w];
    int tot = wave_off[0] + wave_off[1] + wave_off[2] + wave_off[3];
    if (p) {
      int pos = base + off + pre;
      if (pos < CAPC) {
        tok_idx[(size_t)e * CAPC + pos] = t;
        tok_g[(size_t)e * CAPC + pos] = g;
        tok_slot[(size_t)e * CAPC + pos] = slotm[(size_t)t * NE + e];
      }
    }
    base += tot;
    __syncthreads();
  }
  if (tid == 0) counts[e] = min(base, CAPC);
}

// ---------------- expert GEMM: 128x128x32, bf16 MFMA, 3-deep pipeline --------------
// A: bf16 rows via global_load_lds (gathered for GEMM1). B: fp32 weights reg-staged.
// EPI: 0 = bias+gelu -> bf16   1 = bias -> bf16   2 = (bias)*g scatter -> f32 ydense
template<int KD, int ND, bool AGATHER, int EPI>
__global__ __launch_bounds__(256) void moe_gemm(
    const unsigned short* __restrict__ Abf, const float* __restrict__ Bw,
    const float* __restrict__ bias, void* __restrict__ Outp,
    const int* __restrict__ tok_idx, const float* __restrict__ tok_g,
    const int* __restrict__ tok_slot, const int* __restrict__ counts)
{
  const int e = blockIdx.z;
  const int cnt = counts[e];
  const int m0 = blockIdx.y * 128;
  if (m0 >= cnt) return;
  const int n0 = blockIdx.x * 128;
  const int tid = threadIdx.x;

  __shared__ unsigned short Al[3][128][32];
  __shared__ unsigned short Bl[3][128][32];
  __shared__ int   s_tok[128];
  __shared__ float s_g[128];
  __shared__ int   s_slot[128];

  if (EPI == 2 && tid < 128) {
    int gr = m0 + tid;
    if (gr < cnt) {
      s_tok[tid]  = tok_idx[(size_t)e * CAPC + gr];
      s_g[tid]    = tok_g[(size_t)e * CAPC + gr];
      s_slot[tid] = tok_slot[(size_t)e * CAPC + gr];
    }
  }

  // ---- A staging setup: rows tid>>2 and 64+(tid>>2), 16B chunk tid&3 ----
  const int ar0 = tid >> 2;
  const int ac  = (tid & 3) * 8;             // bf16 offset of this lane's 16B chunk
  size_t arow0, arow1;
  if (AGATHER) {
    int g0 = m0 + ar0, g1 = m0 + 64 + ar0;
    int t0i = (g0 < cnt) ? tok_idx[(size_t)e * CAPC + g0] : 0;
    int t1i = (g1 < cnt) ? tok_idx[(size_t)e * CAPC + g1] : 0;
    arow0 = (size_t)t0i * KD; arow1 = (size_t)t1i * KD;
  } else {
    arow0 = ((size_t)e * CAPC + m0 + ar0) * KD;
    arow1 = arow0 + (size_t)64 * KD;
  }
  const unsigned short* ap0 = Abf + arow0 + ac;
  const unsigned short* ap1 = Abf + arow1 + ac;
  const int awb = (tid & 192) * 8;           // wave-uniform LDS base (ushort units)

  // ---- B staging setup: lane covers rows {2l,2l+1}, k-range 8w..8w+7 ----
  const int l = tid & 63, w = tid >> 6;
  const float* bp = Bw + (size_t)e * KD * ND + (size_t)(8 * w) * ND + n0 + 2 * l;
  const int bphys = (w ^ (l & 3)) * 8;       // XOR-swizzled phys chunk (bf16 units)
  const int brow = 2 * l;

  auto stageA = [&](int kt, unsigned short* Abuf) {
    glds16(Abuf + awb,        ap0 + kt * 32);
    glds16(Abuf + 2048 + awb, ap1 + kt * 32);
  };
  float2 bregE[8], bregO[8];
  auto loadB = [&](int kt, float2* br) {
    const float* p = bp + (size_t)kt * 32 * ND;
    #pragma unroll
    for (int j = 0; j < 8; j++) br[j] = *(const float2*)(p + (size_t)j * ND);
  };
  auto writeB = [&](unsigned short* Bbuf, const float2* br) {
    union { bf16x8 v; unsigned short u[8]; } pa, pb;
    #pragma unroll
    for (int j = 0; j < 8; j++) { pa.u[j] = f2bf(br[j].x); pb.u[j] = f2bf(br[j].y); }
    *(bf16x8*)(Bbuf + brow * 32 + bphys)       = pa.v;
    *(bf16x8*)(Bbuf + (brow + 1) * 32 + bphys) = pb.v;
  };

  // ---- MFMA setup ----
  const int lane = tid & 63, wv = tid >> 6;
  const int wm = (wv >> 1) * 64, wn = (wv & 1) * 64;
  const int li = lane & 15, lg = lane >> 4;

  f32x4 acc[4][4];
  #pragma unroll
  for (int i = 0; i < 4; i++)
    #pragma unroll
    for (int j = 0; j < 4; j++) acc[i][j] = (f32x4){0.f, 0.f, 0.f, 0.f};

  auto step = [&](const unsigned short* Abuf, const unsigned short* Bbuf) {
    bf16x8 afr[4], bfr[4];
    #pragma unroll
    for (int mi = 0; mi < 4; mi++)
      afr[mi] = *(const bf16x8*)(Abuf + (wm + mi * 16 + li) * 32 + lg * 8);
    #pragma unroll
    for (int ni = 0; ni < 4; ni++) {
      int rb = wn + ni * 16 + li;
      bfr[ni] = *(const bf16x8*)(Bbuf + rb * 32 + ((lg ^ ((rb >> 1) & 3)) * 8));
    }
    #pragma unroll
    for (int mi = 0; mi < 4; mi++)
      #pragma unroll
      for (int ni = 0; ni < 4; ni++)
        acc[mi][ni] = __builtin_amdgcn_mfma_f32_16x16x32_bf16(afr[mi], bfr[ni], acc[mi][ni], 0, 0, 0);
  };

  unsigned short *Ac = &Al[0][0][0], *An = &Al[1][0][0], *A2 = &Al[2][0][0];
  unsigned short *Bc = &Bl[0][0][0], *Bn = &Bl[1][0][0], *B2 = &Bl[2][0][0];

  constexpr int NK = KD / 32;   // even for all instantiations
  stageA(0, Ac); loadB(0, bregE);
  stageA(1, An); loadB(1, bregO);
  writeB(Bc, bregE);            // compiler waits counted-vmcnt for bregE (tile-1 loads stay in flight)
  BAR();

  for (int kt = 0; kt < NK; kt += 2) {
    // even sub-iter: compute tile kt
    if (kt + 2 < NK) { stageA(kt + 2, A2); loadB(kt + 2, bregE); }
    step(Ac, Bc);
    writeB(Bn, bregO);          // tile kt+1 (kt+1 < NK always: NK even)
    BAR();
    { unsigned short* t = Ac; Ac = An; An = A2; A2 = t; }
    { unsigned short* t = Bc; Bc = Bn; Bn = B2; B2 = t; }
    // odd sub-iter: compute tile kt+1
    if (kt + 3 < NK) { stageA(kt + 3, A2); loadB(kt + 3, bregO); }
    step(Ac, Bc);
    if (kt + 2 < NK) writeB(Bn, bregE);
    BAR();
    { unsigned short* t = Ac; Ac = An; An = A2; A2 = t; }
    { unsigned short* t = Bc; Bc = Bn; Bn = B2; B2 = t; }
  }

  // ---- epilogue ----
  const float* bpb = bias + (size_t)e * ND;
  #pragma unroll
  for (int mi = 0; mi < 4; mi++) {
    #pragma unroll
    for (int ni = 0; ni < 4; ni++) {
      const int ncol = n0 + wn + ni * 16 + li;
      const float bb = bpb[ncol];
      #pragma unroll
      for (int q = 0; q < 4; q++) {
        const int r = wm + mi * 16 + lg * 4 + q;
        const int gr = m0 + r;
        if (gr < cnt) {
          float v = acc[mi][ni][q] + bb;
          if (EPI == 0) {
            v = gelu_exact(v);
            ((unsigned short*)Outp)[((size_t)e * CAPC + gr) * ND + ncol] = f2bf(v);
          } else if (EPI == 1) {
            ((unsigned short*)Outp)[((size_t)e * CAPC + gr) * ND + ncol] = f2bf(v);
          } else {
            ((float*)Outp)[((size_t)s_tok[r] * KTOP + s_slot[r]) * OD + ncol] = v * s_g[r];
          }
        }
      }
    }
  }
}

// ---------------- combine 8 slots + LayerNorm -------------------------------------
__global__ __launch_bounds__(256) void combine_ln(
    const float* __restrict__ yd, const float* __restrict__ lw,
    const float* __restrict__ lb, float* __restrict__ out)
{
  const int t = blockIdx.x, tid = threadIdx.x;
  float v[3];
  #pragma unroll
  for (int i = 0; i < 3; i++) {
    const int c = tid + 256 * i;
    float s = 0.f;
    #pragma unroll
    for (int j = 0; j < KTOP; j++) s += yd[((size_t)t * KTOP + j) * OD + c];
    v[i] = s;
  }
  float s1 = v[0] + v[1] + v[2];
  float s2 = v[0] * v[0] + v[1] * v[1] + v[2] * v[2];
  #pragma unroll
  for (int off = 32; off > 0; off >>= 1) {
    s1 += __shfl_xor(s1, off);
    s2 += __shfl_xor(s2, off);
  }
  __shared__ float as1[4], as2[4];
  const int lane = tid & 63, wv = tid >> 6;
  if (lane == 0) { as1[wv] = s1; as2[wv] = s2; }
  __syncthreads();
  s1 = as1[0] + as1[1] + as1[2] + as1[3];
  s2 = as2[0] + as2[1] + as2[2] + as2[3];
  const float mu = s1 * (1.f / OD);
  const float var = s2 * (1.f / OD) - mu * mu;
  const float rstd = rsqrtf(var + 1e-5f);
  #pragma unroll
  for (int i = 0; i < 3; i++) {
    const int c = tid + 256 * i;
    out[(size_t)t * OD + c] = (v[i] - mu) * rstd * lw[c] + lb[c];
  }
}

extern "C" void kernel_launch(void* const* d_in, const int* in_sizes, int n_in,
                              void* d_out, int out_size, void* d_ws, size_t ws_size,
                              hipStream_t stream) {
  const float* x     = (const float*)d_in[0];
  const float* noise = (const float*)d_in[1];
  const float* Wr    = (const float*)d_in[2];
  const float* br    = (const float*)d_in[3];
  const float* Wn    = (const float*)d_in[4];
  const float* bn    = (const float*)d_in[5];
  const float* W1    = (const float*)d_in[6];
  const float* b1    = (const float*)d_in[7];
  const float* W2    = (const float*)d_in[8];
  const float* b2    = (const float*)d_in[9];
  const float* W3    = (const float*)d_in[10];
  const float* b3    = (const float*)d_in[11];
  const float* Wo    = (const float*)d_in[12];
  const float* bo    = (const float*)d_in[13];
  const float* lw    = (const float*)d_in[14];
  const float* lb    = (const float*)d_in[15];
  float* out = (float*)d_out;

  char* ws = (char*)d_ws;
  constexpr size_t OFF_GATE = 0;
  constexpr size_t OFF_SLOT = OFF_GATE + (size_t)T_TOK * NE * 4;
  constexpr size_t OFF_TIDX = OFF_SLOT + (size_t)T_TOK * NE * 4;
  constexpr size_t OFF_TG   = OFF_TIDX + (size_t)NE * CAPC * 4;
  constexpr size_t OFF_TSL  = OFF_TG + (size_t)NE * CAPC * 4;
  constexpr size_t OFF_CNT  = OFF_TSL + (size_t)NE * CAPC * 4;
  constexpr size_t OFF_YD   = ((OFF_CNT + NE * 4) + 255) & ~(size_t)255;
  constexpr size_t SZ_YD    = (size_t)T_TOK * KTOP * OD * 4;
  constexpr size_t OFF_H1   = OFF_YD + SZ_YD;
  constexpr size_t OFF_H2   = OFF_H1 + (size_t)NE * CAPC * HD * 2;
  constexpr size_t OFF_H3   = OFF_H2 + (size_t)NE * CAPC * HD * 2;
  constexpr size_t OFF_XBF  = OFF_H3 + (size_t)NE * CAPC * BTD * 2;

  float* gate = (float*)(ws + OFF_GATE);
  int*   slot = (int*)(ws + OFF_SLOT);
  int*   tidx = (int*)(ws + OFF_TIDX);
  float* tg   = (float*)(ws + OFF_TG);
  int*   tsl  = (int*)(ws + OFF_TSL);
  int*   cnts = (int*)(ws + OFF_CNT);
  float* yd   = (float*)(ws + OFF_YD);
  unsigned short* h1  = (unsigned short*)(ws + OFF_H1);
  unsigned short* h2  = (unsigned short*)(ws + OFF_H2);
  unsigned short* h3  = (unsigned short*)(ws + OFF_H3);
  unsigned short* xbf = (unsigned short*)(ws + OFF_XBF);

  hipMemsetAsync(yd, 0, SZ_YD, stream);
  cvt_x<<<T_TOK * DIN / 4 / 256, 256, 0, stream>>>(x, xbf);
  router_kernel<<<T_TOK / 8, 256, 0, stream>>>(x, noise, Wr, br, Wn, bn, gate, slot);
  dispatch_kernel<<<NE, 256, 0, stream>>>(gate, slot, tidx, tg, tsl, cnts);
  moe_gemm<DIN, HD, true, 0><<<dim3(HD / 128, CAPC / 128, NE), 256, 0, stream>>>(
      xbf, W1, b1, h1, tidx, tg, tsl, cnts);
  moe_gemm<HD, HD, false, 0><<<dim3(HD / 128, CAPC / 128, NE), 256, 0, stream>>>(
      h1, W2, b2, h2, tidx, tg, tsl, cnts);
  moe_gemm<HD, BTD, false, 1><<<dim3(BTD / 128, CAPC / 128, NE), 256, 0, stream>>>(
      h2, W3, b3, h3, tidx, tg, tsl, cnts);
  moe_gemm<BTD, OD, false, 2><<<dim3(OD / 128, CAPC / 128, NE), 256, 0, stream>>>(
      h3, Wo, bo, yd, tidx, tg, tsl, cnts);
  combine_ln<<<T_TOK, 256, 0, stream>>>(yd, lw, lb, out);
}